// Round 6
// baseline (118.901 us; speedup 1.0000x reference)
//
#include <hip/hip_runtime.h>

// DAREController route(is_visual=True, training=True)
// B=256 rows, S=32768 tokens.
//
// R5 -> R6: split into two kernels to fix streaming occupancy.
//  K1 dare_select (256 x 1024, 1 block/row): one read pass (imp+mask),
//     4-pass radix select -> exact kth-largest key; writes per-row
//     threshold/kpos/stats-init + packed mm-bitmap (1 MB) to d_ws.
//  K2 dare_write (2048 x 256, 8 blocks/row -> 32 waves/CU): re-reads imp +
//     bitmap, writes keep mask at full occupancy, global-atomic row stats.
//  dare_losses unchanged.

#define NB 256
#define NS 32768
#define KAPPA 64
#define NT 1024
#define NW (NT / 64)        // 16 waves in K1
#define HP 257              // hist copy stride (bank-rotating)
#define V4 (NS / NT / 4)    // 8 vec4 per thread in K1

// K2 geometry: 8 blocks per row, 256 threads, 4096 cols per block
#define K2B 256
#define K2SPLIT 8
#define K2V4 (NS / K2SPLIT / K2B / 4)   // 4 vec4 per thread

typedef float f32x4 __attribute__((ext_vector_type(4)));
typedef int   i32x4 __attribute__((ext_vector_type(4)));

// ws layout (floats/words):
//   stats  : f32 [256][4]   @ byte 0      (K1 inits, K2 accumulates)
//   thresh : u32 [256]      @ byte 4096
//   kposa  : u32 [256]      @ byte 5120
//   bitmap : u32 [256][1024]@ byte 8192   (packed mm bits, col-major nibbles)
#define WS_THRESH (4096 / 4)
#define WS_KPOS   (5120 / 4)
#define WS_BM     (8192 / 4)

__device__ __forceinline__ unsigned int fkey(float f) {
    unsigned int u = __float_as_uint(f);
    return (u & 0x80000000u) ? ~u : (u | 0x80000000u);  // monotone: bigger float -> bigger key
}

__global__ __launch_bounds__(NT) void dare_select(const float* __restrict__ imp,
                                                  const int* __restrict__ mask,
                                                  unsigned int* __restrict__ ws) {
    __shared__ unsigned int hist0[NW * HP];   // per-wave pass-0 histograms
    __shared__ unsigned int hist[256];        // passes 1..3
    __shared__ unsigned int bm[NS / 32];      // packed mm bitmap (4 KB)
    __shared__ unsigned int wtot[4];
    __shared__ unsigned int sh_mm, sh_eff;
    __shared__ unsigned int sh_pref;
    __shared__ unsigned int sh_rem;

    const int row = blockIdx.x;
    const int tid = threadIdx.x;
    const int lane = tid & 63;
    const int wid = tid >> 6;
    const f32x4* rimp4  = (const f32x4*)(imp  + (size_t)row * NS);
    const i32x4* rmask4 = (const i32x4*)(mask + (size_t)row * NS);

    for (int i = tid; i < NW * HP; i += NT) hist0[i] = 0;
    if (tid < 256) hist[tid] = 0;
    bm[tid] = 0;
    if (tid == 0) { sh_mm = 0; sh_eff = 0; sh_pref = 0; sh_rem = 1; }
    __syncthreads();

    // ---- one streaming read pass: keys + bits ----
    unsigned int keys[V4 * 4];
    unsigned int effbits = 0, mmbits = 0;

    #pragma unroll
    for (int i = 0; i < V4; i++) {
        const int idx4 = tid + i * NT;
        const f32x4 v = rimp4[idx4];
        const i32x4 m = rmask4[idx4];
        #pragma unroll
        for (int j = 0; j < 4; j++) {
            const int e = i * 4 + j;
            const int col = idx4 * 4 + j;
            keys[e] = fkey(v[j]);
            const bool mm  = (m[j] != 0);
            const bool eff = mm && (col >= KAPPA);
            mmbits  |= (mm  ? 1u : 0u) << e;
            effbits |= (eff ? 1u : 0u) << e;
        }
    }

    // pass-0 hist + bitmap
    unsigned int* myhist = &hist0[wid * HP];
    #pragma unroll
    for (int e = 0; e < V4 * 4; e++) {
        if ((effbits >> e) & 1u) atomicAdd(&myhist[keys[e] >> 24], 1u);
    }
    #pragma unroll
    for (int i = 0; i < V4; i++) {
        const int idx4 = tid + i * NT;
        const unsigned int nib = (mmbits >> (i * 4)) & 0xFu;
        atomicOr(&bm[idx4 >> 3], nib << ((idx4 & 7) * 4));
    }

    int mm_local  = __popc(mmbits);
    int eff_local = __popc(effbits);
    #pragma unroll
    for (int off = 32; off; off >>= 1) {
        mm_local  += __shfl_down(mm_local, off);
        eff_local += __shfl_down(eff_local, off);
    }
    if (lane == 0) {
        atomicAdd(&sh_mm,  (unsigned int)mm_local);
        atomicAdd(&sh_eff, (unsigned int)eff_local);
    }
    __syncthreads();

    // ---- 4 radix passes, parallel suffix-scan bin select ----
    #pragma unroll
    for (int pass = 0; pass < 4; pass++) {
        const int shift = 24 - 8 * pass;

        if (pass > 0) {
            if (tid < 256) hist[tid] = 0;
            __syncthreads();
            const unsigned int pmask = 0xFFFFFFFFu << (shift + 8);
            const unsigned int pref = sh_pref;
            #pragma unroll
            for (int e = 0; e < V4 * 4; e++) {
                const bool match = ((effbits >> e) & 1u) && ((keys[e] & pmask) == pref);
                if (match) atomicAdd(&hist[(keys[e] >> shift) & 0xFFu], 1u);
            }
            __syncthreads();
        }

        unsigned int h = 0, s = 0;
        if (tid < 256) {
            if (pass == 0) {
                #pragma unroll
                for (int c = 0; c < NW; c++) h += hist0[c * HP + tid];
            } else {
                h = hist[tid];
            }
            s = h;
            #pragma unroll
            for (int off = 1; off < 64; off <<= 1) {
                const unsigned int t = __shfl_down(s, off);
                if (lane + off < 64) s += t;
            }
            if (lane == 0) wtot[tid >> 6] = s;
        }
        __syncthreads();
        if (tid < 256) {
            unsigned int sfull = s;
            for (int w = (tid >> 6) + 1; w < 4; w++) sfull += wtot[w];
            unsigned int rem;
            if (pass == 0) {
                const float target = fmaxf((float)sh_mm * 0.5f, 1.0f);
                const int k = min((int)target, (int)sh_eff);
                rem = (unsigned int)max(k, 1);
            } else {
                rem = sh_rem;
            }
            if (sfull >= rem && (sfull - h) < rem) {
                sh_pref = (pass == 0) ? ((unsigned int)tid << 24)
                                      : (sh_pref | ((unsigned int)tid << shift));
                sh_rem = rem - (sfull - h);
            }
        }
        __syncthreads();
    }

    // ---- emit: bitmap, threshold, kpos, stats init ----
    ws[WS_BM + row * (NS / 32) + tid] = bm[tid];
    if (tid == 0) {
        const float target = fmaxf((float)sh_mm * 0.5f, 1.0f);
        const int k = min((int)target, (int)sh_eff);
        ws[WS_THRESH + row] = sh_pref;
        ws[WS_KPOS + row] = (k > 0) ? 1u : 0u;
        float* stats = (float*)ws;
        stats[row * 4 + 0] = 0.0f;             // kept (K2 accumulates)
        stats[row * 4 + 1] = (float)sh_mm;     // mm count
        stats[row * 4 + 2] = 0.0f;             // ndrop
        stats[row * 4 + 3] = 0.0f;             // drop sum
    }
}

__global__ __launch_bounds__(K2B) void dare_write(const float* __restrict__ imp,
                                                  const unsigned int* __restrict__ ws,
                                                  float* __restrict__ keep) {
    __shared__ float w_k[4], w_n[4], w_d[4];

    const int row = blockIdx.x >> 3;         // 8 blocks per row
    const int q   = blockIdx.x & 7;
    const int tid = threadIdx.x;
    const int lane = tid & 63;

    const unsigned int thresh = ws[WS_THRESH + row];
    const bool kpos = ws[WS_KPOS + row] != 0u;
    const unsigned int* rbm = ws + WS_BM + row * (NS / 32);

    const f32x4* rimp4  = (const f32x4*)(imp  + (size_t)row * NS);
    f32x4*       rkeep4 = (f32x4*)      (keep + (size_t)row * NS);

    int kept_l = 0, ndrop_l = 0;
    float dsum_l = 0.0f;

    #pragma unroll
    for (int i = 0; i < K2V4; i++) {
        const int idx4 = q * (NS / K2SPLIT / 4) + tid + i * K2B;
        const f32x4 v = rimp4[idx4];
        const unsigned int nib = (rbm[idx4 >> 3] >> ((idx4 & 7) * 4)) & 0xFu;
        f32x4 o;
        #pragma unroll
        for (int j = 0; j < 4; j++) {
            const int col = idx4 * 4 + j;
            const bool mm  = (nib >> j) & 1u;
            const bool eff = mm && (col >= KAPPA);
            const bool hard = eff && kpos && (fkey(v[j]) >= thresh);
            const bool kp = (col < KAPPA) || hard;
            o[j] = kp ? 1.0f : 0.0f;
            kept_l += (kp && mm) ? 1 : 0;
            const bool drop = mm && !kp;
            ndrop_l += drop ? 1 : 0;
            dsum_l += drop ? v[j] : 0.0f;
        }
        rkeep4[idx4] = o;
    }

    #pragma unroll
    for (int off = 32; off; off >>= 1) {
        kept_l  += __shfl_down(kept_l, off);
        ndrop_l += __shfl_down(ndrop_l, off);
        dsum_l  += __shfl_down(dsum_l, off);
    }
    const int wid = tid >> 6;
    if (lane == 0) { w_k[wid] = (float)kept_l; w_n[wid] = (float)ndrop_l; w_d[wid] = dsum_l; }
    __syncthreads();
    if (tid == 0) {
        float sk = 0.f, sn = 0.f, sd = 0.f;
        for (int w = 0; w < 4; w++) { sk += w_k[w]; sn += w_n[w]; sd += w_d[w]; }
        float* stats = (float*)ws;
        atomicAdd(&stats[row * 4 + 0], sk);
        atomicAdd(&stats[row * 4 + 2], sn);
        atomicAdd(&stats[row * 4 + 3], sd);
    }
}

__global__ __launch_bounds__(256) void dare_losses(const float* __restrict__ stats,
                                                   float* __restrict__ out) {
    __shared__ float w_a[4], w_h[4], w_n[4], w_d[4];
    const int tid = threadIdx.x;   // one thread per row
    const float kept = stats[tid * 4 + 0];
    const float mmc  = stats[tid * 4 + 1];
    const float nd   = stats[tid * 4 + 2];
    const float ds   = stats[tid * 4 + 3];
    const float ratio = kept / (mmc + 1e-6f);
    float a = fabsf(ratio - 0.5f);          // |ratio - rho|
    float h = fmaxf(0.5f - ratio, 0.0f);    // relu(rho - ratio)
    float n = nd, d = ds;
    #pragma unroll
    for (int off = 32; off; off >>= 1) {
        a += __shfl_down(a, off);
        h += __shfl_down(h, off);
        n += __shfl_down(n, off);
        d += __shfl_down(d, off);
    }
    const int wid = tid >> 6, lane = tid & 63;
    if (lane == 0) { w_a[wid] = a; w_h[wid] = h; w_n[wid] = n; w_d[wid] = d; }
    __syncthreads();
    if (tid == 0) {
        float sa = 0.f, shh = 0.f, sn = 0.f, sd = 0.f;
        for (int w = 0; w < 4; w++) { sa += w_a[w]; shh += w_h[w]; sn += w_n[w]; sd += w_d[w]; }
        out[0] = sa / (float)NB;                                        // 1.0 * loss_ratio
        out[1] = (sn > 0.0f) ? 0.1f * (sd / fmaxf(sn, 1.0f)) : 0.0f;    // 0.1 * loss_soft
        out[2] = shh / (float)NB;                                       // 1.0 * loss_hard
    }
}

extern "C" void kernel_launch(void* const* d_in, const int* in_sizes, int n_in,
                              void* d_out, int out_size, void* d_ws, size_t ws_size,
                              hipStream_t stream) {
    const float* imp  = (const float*)d_in[0];
    const int*   mask = (const int*)d_in[1];
    float* out = (float*)d_out;
    unsigned int* ws = (unsigned int*)d_ws;

    dare_select<<<NB, NT, 0, stream>>>(imp, mask, ws);
    dare_write<<<NB * K2SPLIT, K2B, 0, stream>>>(imp, ws, out);
    dare_losses<<<1, 256, 0, stream>>>((const float*)ws, out + (size_t)NB * NS);
}

// Round 7
// 111.339 us; speedup vs baseline: 1.0679x; 1.0679x over previous
//
#include <hip/hip_runtime.h>

// DAREController route(is_visual=True, training=True)
// B=256 rows, S=32768 tokens. One block per row.
//
// R6 -> R7: single-pass coarse select + wave-0 finisher.
//  - ONE 2048-bin histogram on the key's top 11 bits (sign+exp+2 mant) decides
//    the coarse bucket b0 of the k-th largest valid key after a single scan.
//  - Elements with bucket != b0 have keep/drop known immediately -> stored in
//    the "early" loop (~97% of traffic), overlapping the finisher.
//  - Bucket-b0 candidates (~600/row for N(0,1) data) are appended to an LDS
//    array; wave 0 alone bit-selects the exact low-21 bits of the k-th key
//    via __ballot (no block barriers in the finisher).
//  - Deferred vec4s (those containing a candidate) are stored in a tail loop.
//  - Barriers: ~14 -> 7; select VALU work ~3x lower; stores start earlier.
//  - cand[NS] (128 KB LDS) covers ANY input (no overflow path) and enforces
//    1 block/CU, guaranteeing balanced dispatch for grid == #CUs.

#define NB 256
#define NS 32768
#define KAPPA 64
#define NT 1024
#define V4 (NS / NT / 4)      // 8 vec4 per thread
#define NBIN 2048             // top-11-bit buckets
#define NSEG 256              // scan segments (threads)
#define SEGW (NBIN / NSEG)    // 8 bins per scan thread

typedef float f32x4 __attribute__((ext_vector_type(4)));
typedef int   i32x4 __attribute__((ext_vector_type(4)));

__device__ __forceinline__ unsigned int fkey(float f) {
    unsigned int u = __float_as_uint(f);
    return (u & 0x80000000u) ? ~u : (u | 0x80000000u);  // monotone: bigger float -> bigger key
}

__device__ __forceinline__ float unkey(unsigned int k) {
    unsigned int u = (k & 0x80000000u) ? (k ^ 0x80000000u) : ~k;
    return __uint_as_float(u);
}

__global__ __launch_bounds__(NT) void dare_rows(const float* __restrict__ imp,
                                                const int* __restrict__ mask,
                                                float* __restrict__ keep,
                                                float* __restrict__ stats) {
    __shared__ unsigned int hist[NBIN];     // 8 KB
    __shared__ unsigned int cand[NS];       // 128 KB: candidate keys (bucket == b0)
    __shared__ unsigned int wtot[4];
    __shared__ unsigned int sh_mm, sh_eff, sh_cand;
    __shared__ unsigned int sh_b0, sh_rem, sh_thresh;
    __shared__ unsigned int sh_kept, sh_ndrop;
    __shared__ float sh_dsum;

    const int row = blockIdx.x;
    const int tid = threadIdx.x;
    const int lane = tid & 63;
    const int wid = tid >> 6;
    const f32x4* rimp4  = (const f32x4*)(imp  + (size_t)row * NS);
    const i32x4* rmask4 = (const i32x4*)(mask + (size_t)row * NS);
    f32x4*       rkeep4 = (f32x4*)      (keep + (size_t)row * NS);

    hist[tid] = 0;
    hist[tid + NT] = 0;
    if (tid == 0) {
        sh_mm = 0; sh_eff = 0; sh_cand = 0;
        sh_b0 = 0; sh_rem = 1; sh_thresh = 0;
        sh_kept = 0; sh_ndrop = 0; sh_dsum = 0.0f;
    }
    __syncthreads();   // B1

    // ---- Phase 1: one streaming read -> keys in regs ----
    unsigned int keys[V4 * 4];
    unsigned int effbits = 0, mmbits = 0;

    #pragma unroll
    for (int i = 0; i < V4; i++) {
        const int idx4 = tid + i * NT;
        const f32x4 v = rimp4[idx4];
        const i32x4 m = rmask4[idx4];
        #pragma unroll
        for (int j = 0; j < 4; j++) {
            const int e = i * 4 + j;
            const int col = idx4 * 4 + j;
            keys[e] = fkey(v[j]);
            const bool mm  = (m[j] != 0);
            const bool eff = mm && (col >= KAPPA);
            mmbits  |= (mm  ? 1u : 0u) << e;
            effbits |= (eff ? 1u : 0u) << e;
        }
    }

    // single histogram pass (top 11 bits)
    #pragma unroll
    for (int e = 0; e < V4 * 4; e++) {
        if ((effbits >> e) & 1u) atomicAdd(&hist[keys[e] >> 21], 1u);
    }

    int mm_local  = __popc(mmbits);
    int eff_local = __popc(effbits);
    #pragma unroll
    for (int off = 32; off; off >>= 1) {
        mm_local  += __shfl_down(mm_local, off);
        eff_local += __shfl_down(eff_local, off);
    }
    if (lane == 0) {
        atomicAdd(&sh_mm,  (unsigned int)mm_local);
        atomicAdd(&sh_eff, (unsigned int)eff_local);
    }
    __syncthreads();   // B2 (hist + counts ready)

    // ---- Phase 2: coarse scan, 256 threads x 8 bins each ----
    unsigned int r[SEGW];
    unsigned int hsum = 0, s = 0;
    if (tid < NSEG) {
        #pragma unroll
        for (int b = 0; b < SEGW; b++) { r[b] = hist[tid * SEGW + b]; hsum += r[b]; }
        s = hsum;
        #pragma unroll
        for (int off = 1; off < 64; off <<= 1) {
            const unsigned int t = __shfl_down(s, off);
            if (lane + off < 64) s += t;
        }
        if (lane == 0) wtot[tid >> 6] = s;
    }
    __syncthreads();   // B3 (wtot ready)
    if (tid < NSEG) {
        unsigned int sfull = s;
        for (int w = (tid >> 6) + 1; w < 4; w++) sfull += wtot[w];
        const float target = fmaxf((float)sh_mm * 0.5f, 1.0f);
        const int k = min((int)target, (int)sh_eff);
        const unsigned int rem = (unsigned int)max(k, 1);
        const unsigned int above = sfull - hsum;   // count in higher segments
        if (sfull >= rem && above < rem) {
            // crossing segment: walk bins high -> low in registers
            unsigned int cum = above;
            #pragma unroll
            for (int b = SEGW - 1; b >= 0; b--) {
                if (cum + r[b] >= rem) { sh_b0 = tid * SEGW + b; sh_rem = rem - cum; break; }
                cum += r[b];
            }
        }
    }
    __syncthreads();   // B4 (b0, rem ready)

    // ---- Phase 3a: early stores for decided vec4s + candidate append ----
    const unsigned int b0 = sh_b0;
    const bool kpos = (sh_eff > 0);

    int kept_l = 0, ndrop_l = 0;
    float dsum_l = 0.0f;
    unsigned int defer = 0;

    #pragma unroll
    for (int i = 0; i < V4; i++) {
        const int idx4 = tid + i * NT;
        unsigned int cm = 0;
        #pragma unroll
        for (int j = 0; j < 4; j++) {
            const int e = i * 4 + j;
            const bool eff = (effbits >> e) & 1u;
            const bool is_cand = kpos && eff && ((keys[e] >> 21) == b0);
            cm |= (is_cand ? 1u : 0u) << j;
        }
        if (cm) {
            defer |= 1u << i;
            #pragma unroll
            for (int j = 0; j < 4; j++) {
                if ((cm >> j) & 1u) {
                    const unsigned int pos = atomicAdd(&sh_cand, 1u);
                    cand[pos] = keys[i * 4 + j];
                }
            }
        } else {
            f32x4 o;
            #pragma unroll
            for (int j = 0; j < 4; j++) {
                const int e = i * 4 + j;
                const int col = idx4 * 4 + j;
                const bool mm  = (mmbits >> e) & 1u;
                const bool eff = (effbits >> e) & 1u;
                const bool hard = kpos && eff && ((keys[e] >> 21) > b0);
                const bool kp = (col < KAPPA) || hard;
                o[j] = kp ? 1.0f : 0.0f;
                kept_l += (kp && mm) ? 1 : 0;
                const bool drop = mm && !kp;
                ndrop_l += drop ? 1 : 0;
                dsum_l += drop ? unkey(keys[e]) : 0.0f;
            }
            rkeep4[idx4] = o;
        }
    }
    __syncthreads();   // B5 (cand array complete)

    // ---- Phase 3b: wave-0 ballot bit-select over candidates ----
    if (tid < 64) {
        const unsigned int cnt = sh_cand;
        if (cnt > 0) {
            unsigned int rem = sh_rem;
            unsigned int pref = 0;
            const int slots = (int)((cnt + 63u) >> 6);
            unsigned int lowreg[16];
            #pragma unroll
            for (int sl = 0; sl < 16; sl++) {
                const unsigned int idx = (unsigned int)lane + ((unsigned int)sl << 6);
                lowreg[sl] = (idx < cnt) ? (cand[idx] & 0x1FFFFFu) : 0xFFFFFFFFu;
            }
            for (int bit = 20; bit >= 0; bit--) {
                const unsigned int hi = pref >> (bit + 1);
                unsigned int cnt1 = 0;
                for (int sl = 0; sl < slots; sl++) {
                    unsigned int lw;
                    if (sl < 16) lw = lowreg[sl];
                    else {
                        const unsigned int idx = (unsigned int)lane + ((unsigned int)sl << 6);
                        lw = (idx < cnt) ? (cand[idx] & 0x1FFFFFu) : 0xFFFFFFFFu;
                    }
                    const bool m = (lw >> (bit + 1)) == hi && ((lw >> bit) & 1u);
                    cnt1 += (unsigned int)__popcll(__ballot(m));
                }
                if (cnt1 >= rem) pref |= 1u << bit; else rem -= cnt1;
            }
            if (lane == 0) sh_thresh = (b0 << 21) | pref;
        }
    }
    __syncthreads();   // B6 (thresh ready)

    // ---- Phase 3c: tail — deferred vec4s with exact threshold ----
    const unsigned int thresh = sh_thresh;
    #pragma unroll
    for (int i = 0; i < V4; i++) {
        if ((defer >> i) & 1u) {
            const int idx4 = tid + i * NT;
            f32x4 o;
            #pragma unroll
            for (int j = 0; j < 4; j++) {
                const int e = i * 4 + j;
                const int col = idx4 * 4 + j;
                const bool mm  = (mmbits >> e) & 1u;
                const bool eff = (effbits >> e) & 1u;
                const bool hard = kpos && eff && (keys[e] >= thresh);
                const bool kp = (col < KAPPA) || hard;
                o[j] = kp ? 1.0f : 0.0f;
                kept_l += (kp && mm) ? 1 : 0;
                const bool drop = mm && !kp;
                ndrop_l += drop ? 1 : 0;
                dsum_l += drop ? unkey(keys[e]) : 0.0f;
            }
            rkeep4[idx4] = o;
        }
    }

    #pragma unroll
    for (int off = 32; off; off >>= 1) {
        kept_l  += __shfl_down(kept_l, off);
        ndrop_l += __shfl_down(ndrop_l, off);
        dsum_l  += __shfl_down(dsum_l, off);
    }
    if (lane == 0) {
        atomicAdd(&sh_kept,  (unsigned int)kept_l);
        atomicAdd(&sh_ndrop, (unsigned int)ndrop_l);
        atomicAdd(&sh_dsum,  dsum_l);
    }
    __syncthreads();   // B7
    if (tid == 0) {
        stats[row * 4 + 0] = (float)sh_kept;
        stats[row * 4 + 1] = (float)sh_mm;
        stats[row * 4 + 2] = (float)sh_ndrop;
        stats[row * 4 + 3] = sh_dsum;
    }
}

__global__ __launch_bounds__(256) void dare_losses(const float* __restrict__ stats,
                                                   float* __restrict__ out) {
    __shared__ float w_a[4], w_h[4], w_n[4], w_d[4];
    const int tid = threadIdx.x;   // one thread per row
    const float kept = stats[tid * 4 + 0];
    const float mmc  = stats[tid * 4 + 1];
    const float nd   = stats[tid * 4 + 2];
    const float ds   = stats[tid * 4 + 3];
    const float ratio = kept / (mmc + 1e-6f);
    float a = fabsf(ratio - 0.5f);          // |ratio - rho|
    float h = fmaxf(0.5f - ratio, 0.0f);    // relu(rho - ratio)
    float n = nd, d = ds;
    #pragma unroll
    for (int off = 32; off; off >>= 1) {
        a += __shfl_down(a, off);
        h += __shfl_down(h, off);
        n += __shfl_down(n, off);
        d += __shfl_down(d, off);
    }
    const int wid = tid >> 6, lane = tid & 63;
    if (lane == 0) { w_a[wid] = a; w_h[wid] = h; w_n[wid] = n; w_d[wid] = d; }
    __syncthreads();
    if (tid == 0) {
        float sa = 0.f, shh = 0.f, sn = 0.f, sd = 0.f;
        for (int w = 0; w < 4; w++) { sa += w_a[w]; shh += w_h[w]; sn += w_n[w]; sd += w_d[w]; }
        out[0] = sa / (float)NB;                                        // 1.0 * loss_ratio
        out[1] = (sn > 0.0f) ? 0.1f * (sd / fmaxf(sn, 1.0f)) : 0.0f;    // 0.1 * loss_soft
        out[2] = shh / (float)NB;                                       // 1.0 * loss_hard
    }
}

extern "C" void kernel_launch(void* const* d_in, const int* in_sizes, int n_in,
                              void* d_out, int out_size, void* d_ws, size_t ws_size,
                              hipStream_t stream) {
    const float* imp  = (const float*)d_in[0];
    const int*   mask = (const int*)d_in[1];
    float* out   = (float*)d_out;
    float* stats = (float*)d_ws;   // 256 rows * 4 floats = 4 KB

    dare_rows<<<NB, NT, 0, stream>>>(imp, mask, out, stats);
    dare_losses<<<1, 256, 0, stream>>>(stats, out + (size_t)NB * NS);
}